// Round 18
// baseline (129.933 us; speedup 1.0000x reference)
//
#include <hip/hip_runtime.h>
#include <hip/hip_bf16.h>

// attention_84464826843938: additive-attention pooling, MI355X (gfx950)
//
// R18: same-slice co-residency remap (B L1-dedup) + nt-A (from R17).
//  Delivered-bytes invariant: all 2-blk/CU structures pin at ~15 B/cyc/CU
//  (780 MB total -> 82-92us). Only bytes-lever left: co-resident blocks
//  {p, p+256} currently read DIFFERENT B slices; remap so they share the SAME
//  slice -> their per-step 32KB B-tiles are identical -> L1 dedup halves B
//  delivery (B = 2/3 of all bytes). nt-A keeps A out of L1 so the shared B
//  tile (32KB) exactly fits. Mapping: slice=(p>>1)&1, b=((p>>2)<<1)|(p&1).
//  Everything else identical to R17 (R13 geometry: BM=64 BN=256 BK=64,
//  256thr/4waves, wave 64rx64c, reg-staged A, counted vmcnt, 1 barrier/step).

#define B_ 256
#define R_ 64
#define F_ 2048
#define H_ 512
#define DIM_ 512

typedef short bf16x8 __attribute__((ext_vector_type(8)));
typedef float f32x4 __attribute__((ext_vector_type(4)));

__device__ __forceinline__ ushort f2bf(float x) {
  __hip_bfloat16 h = __float2bfloat16(x);
  return __builtin_bit_cast(ushort, h);
}

__device__ __forceinline__ uint2 pack4(float4 x) {
  uint2 r;
  r.x = (uint)f2bf(x.x) | ((uint)f2bf(x.y) << 16);
  r.y = (uint)f2bf(x.z) | ((uint)f2bf(x.w) << 16);
  return r;
}

__device__ __forceinline__ float4 ntload4(const float* p) {
  const __attribute__((ext_vector_type(4))) float* vp =
      reinterpret_cast<const __attribute__((ext_vector_type(4))) float*>(p);
  __attribute__((ext_vector_type(4))) float v = __builtin_nontemporal_load(vp);
  return (float4){v.x, v.y, v.z, v.w};
}

// blocks [0,4096): wpack[((kt*32+ctg)*64 + g*16 + c)*8 + i] = bf16(W_w[kt*32+g*8+i][ctg*16+c])
// blocks [4096,4352): p'[b][d] = prev[b]@W2_w[:,d] + W2_b[d] + W_b[d]
__global__ __launch_bounds__(256) void setup_k(const float* __restrict__ Ww,
                                               ushort* __restrict__ wpack,
                                               const float* __restrict__ prev,
                                               const float* __restrict__ W2w,
                                               const float* __restrict__ W2b,
                                               const float* __restrict__ Wb,
                                               float* __restrict__ pprime) {
  __shared__ float lprev[8][H_];
  if (blockIdx.x < 4096) {
    int idx = blockIdx.x * 256 + threadIdx.x;
    float v = Ww[idx];
    int k = idx >> 9;
    int d = idx & 511;
    int kt = k >> 5, kr = k & 31;
    int g = kr >> 3, i = kr & 7;
    int ctg = d >> 4, c = d & 15;
    size_t dst = ((size_t)((kt * 32 + ctg) * 64 + g * 16 + c)) * 8 + (size_t)i;
    wpack[dst] = f2bf(v);
    return;
  }
  int pb = blockIdx.x - 4096;
  int bg = pb >> 3;
  int d0 = (pb & 7) * 64;
  int t = threadIdx.x;
  const float4* src = reinterpret_cast<const float4*>(prev + (size_t)bg * 8 * H_);
  float4* dst = reinterpret_cast<float4*>(&lprev[0][0]);
  for (int i = t; i < 8 * H_ / 4; i += 256) dst[i] = src[i];
  __syncthreads();
  int d = d0 + (t & 63);
  int bq = t >> 6;
  float a0 = 0.f, a1 = 0.f;
  #pragma unroll 8
  for (int h = 0; h < H_; ++h) {
    float wv = W2w[h * DIM_ + d];
    a0 += lprev[bq][h] * wv;
    a1 += lprev[bq + 4][h] * wv;
  }
  float bias = W2b[d] + Wb[d];
  pprime[(size_t)(bg * 8 + bq) * DIM_ + d] = a0 + bias;
  pprime[(size_t)(bg * 8 + bq + 4) * DIM_ + d] = a1 + bias;
}

__device__ __forceinline__ float fast_tanh(float x) {
  float e = __expf(2.f * x);
  return 1.f - 2.f / (e + 1.f);
}

// sp[b*2+slice][r] = sum_{d in slice's 256 cols} tanh(c[b][r][d]+p'[b][d])*W3[d]
__global__ __launch_bounds__(256, 2) void score_k(const float* __restrict__ feat,
                                                  const ushort* __restrict__ wpack,
                                                  const float* __restrict__ pprime,
                                                  const float* __restrict__ W3,
                                                  float* __restrict__ sp) {
  int p = blockIdx.x;
  int slice = (p >> 1) & 1;             // co-resident pair {p, p+256}: SAME slice
  int b = ((p >> 2) << 1) | (p & 1);    // bijective
  int t = threadIdx.x;
  int wid = t >> 6;                     // 4 waves; wave owns cols [wid*64,+64)
  int l = t & 63;
  int l15 = l & 15, g = l >> 4;
  const float* featB = feat + (size_t)b * R_ * F_;

  // frg[buf][kc*64 + (row ^ kc)] = bf16 A[row][k = kt*64 + kc*8 .. +8]
  __shared__ uint4 frg[2][512];         // 2 x 8 KB double buffer
  __shared__ float lds_part[4][R_];

  f32x4 acc[4][4];
  #pragma unroll
  for (int rt = 0; rt < 4; ++rt)
    #pragma unroll
    for (int ct = 0; ct < 4; ++ct)
      acc[rt][ct] = (f32x4){0.f, 0.f, 0.f, 0.f};

  // ---- A staging: thread t covers float4-chunk c4 = t&15 of rows (t>>4)+16j
  int c4 = t & 15;
  int r16 = t >> 4;
  int kcw = c4 >> 1, half = c4 & 1;
  const float* gaj[4];
  int wij[4];
  #pragma unroll
  for (int j = 0; j < 4; ++j) {
    int r = r16 + 16 * j;
    gaj[j] = featB + (size_t)r * F_ + (size_t)(c4 * 4);
    wij[j] = kcw * 64 + (r ^ kcw);
  }

  // ---- B pointer: frag(kt,s,ct) at wp + kt*32768 + s*16384 + ct*512 (ushorts)
  const ushort* wp = wpack + (size_t)(slice * 16 + wid * 4) * 512 + (size_t)l * 8;

#define LOADA(SET, kt) do {                                          \
    _Pragma("unroll")                                                \
    for (int j_ = 0; j_ < 4; ++j_)                                   \
      SET[j_] = ntload4(gaj[j_] + (size_t)(kt) * 64);                \
  } while (0)

#define CVTW(SET, fb) do {                                           \
    _Pragma("unroll")                                                \
    for (int j_ = 0; j_ < 4; ++j_) {                                 \
      uint2* d_ = reinterpret_cast<uint2*>(&frg[fb][wij[j_]]);       \
      d_[half] = pack4(SET[j_]);                                     \
    }                                                                \
  } while (0)

#define LOADB(dst, kt) do {                                          \
    const ushort* wpk_ = wp + (size_t)(kt) * 32768;                  \
    _Pragma("unroll")                                                \
    for (int s_ = 0; s_ < 2; ++s_)                                   \
      _Pragma("unroll")                                              \
      for (int ct_ = 0; ct_ < 4; ++ct_)                              \
        dst[s_][ct_] = *reinterpret_cast<const uint4*>(              \
            wpk_ + s_ * 16384 + ct_ * 512);                          \
  } while (0)

#define MFMA_STEP(fb, BSET) do {                                     \
    _Pragma("unroll")                                                \
    for (int s_ = 0; s_ < 2; ++s_) {                                 \
      int kc_ = s_ * 4 + g;                                          \
      bf16x8 af_[4];                                                 \
      _Pragma("unroll")                                              \
      for (int rt_ = 0; rt_ < 4; ++rt_)                              \
        af_[rt_] = __builtin_bit_cast(bf16x8,                        \
            frg[fb][kc_ * 64 + ((rt_ * 16 + l15) ^ kc_)]);           \
      _Pragma("unroll")                                              \
      for (int ct_ = 0; ct_ < 4; ++ct_) {                            \
        bf16x8 bv_ = __builtin_bit_cast(bf16x8, BSET[s_][ct_]);      \
        _Pragma("unroll")                                            \
        for (int rt_ = 0; rt_ < 4; ++rt_)                            \
          acc[rt_][ct_] = __builtin_amdgcn_mfma_f32_16x16x32_bf16(   \
              af_[rt_], bv_, acc[rt_][ct_], 0, 0, 0);                \
      }                                                              \
    }                                                                \
  } while (0)

#define WAITBAR(N) do {                                              \
    asm volatile("s_waitcnt vmcnt(" #N ") lgkmcnt(0)" ::: "memory"); \
    __builtin_amdgcn_s_barrier();                                    \
    asm volatile("" ::: "memory");                                   \
  } while (0)

  float4 aS0[4], aS1[4];
  uint4 bA[2][2 * 2], bB[2][2 * 2];

  // prologue: A(0)->aS0, B(0)->bA, A(1)->aS1; drain A(0); cvt -> frg[0]
  LOADA(aS0, 0);
  LOADB(bA, 0);
  LOADA(aS1, 1);
  asm volatile("s_waitcnt vmcnt(12)" ::: "memory");
  CVTW(aS0, 0);

  for (int kt = 0; kt < 28; kt += 2) {
    // even half (tile kt): frg[0], bA
    LOADB(bB, kt + 1);
    LOADA(aS0, kt + 2);
    WAITBAR(12);
    CVTW(aS1, 1);                       // A(kt+1) -> frg[1]
    __builtin_amdgcn_s_setprio(1);
    MFMA_STEP(0, bA);
    __builtin_amdgcn_s_setprio(0);
    // odd half (tile kt+1): frg[1], bB
    LOADB(bA, kt + 2);
    LOADA(aS1, kt + 3);
    WAITBAR(12);
    CVTW(aS0, 0);                       // A(kt+2) -> frg[0]
    __builtin_amdgcn_s_setprio(1);
    MFMA_STEP(1, bB);
    __builtin_amdgcn_s_setprio(0);
  }
  // peel kt=28..31
  LOADB(bB, 29);
  LOADA(aS0, 30);
  WAITBAR(12);
  CVTW(aS1, 1);
  __builtin_amdgcn_s_setprio(1);
  MFMA_STEP(0, bA);
  __builtin_amdgcn_s_setprio(0);

  LOADB(bA, 30);
  LOADA(aS1, 31);
  WAITBAR(12);
  CVTW(aS0, 0);
  __builtin_amdgcn_s_setprio(1);
  MFMA_STEP(1, bB);
  __builtin_amdgcn_s_setprio(0);

  LOADB(bB, 31);
  WAITBAR(8);                           // queue: A(31):4, B(30):8, B(31):8
  CVTW(aS1, 1);
  __builtin_amdgcn_s_setprio(1);
  MFMA_STEP(0, bA);
  __builtin_amdgcn_s_setprio(0);

  WAITBAR(0);
  __builtin_amdgcn_s_setprio(1);
  MFMA_STEP(1, bB);
  __builtin_amdgcn_s_setprio(0);

#undef LOADA
#undef CVTW
#undef LOADB
#undef MFMA_STEP
#undef WAITBAR

  // epilogue: tanh + W3 dot in registers
  // acc[rt][ct][j] = c[row = rt*16 + g*4 + j][col = slice*256 + wid*64 + ct*16 + l15]
  float pp[4], w3v[4];
  #pragma unroll
  for (int ct = 0; ct < 4; ++ct) {
    int col = slice * 256 + wid * 64 + ct * 16 + l15;
    pp[ct] = pprime[b * DIM_ + col];
    w3v[ct] = W3[col];
  }
  #pragma unroll
  for (int rt = 0; rt < 4; ++rt) {
    #pragma unroll
    for (int j = 0; j < 4; ++j) {
      float v = fast_tanh(acc[rt][0][j] + pp[0]) * w3v[0]
              + fast_tanh(acc[rt][1][j] + pp[1]) * w3v[1]
              + fast_tanh(acc[rt][2][j] + pp[2]) * w3v[2]
              + fast_tanh(acc[rt][3][j] + pp[3]) * w3v[3];
      v += __shfl_xor(v, 1);
      v += __shfl_xor(v, 2);
      v += __shfl_xor(v, 4);
      v += __shfl_xor(v, 8);
      if (l15 == 0) lds_part[wid][rt * 16 + g * 4 + j] = v;
    }
  }
  __syncthreads();

  if (t < R_) {
    float s = lds_part[0][t] + lds_part[1][t] + lds_part[2][t] + lds_part[3][t];
    sp[((size_t)b * 2 + slice) * R_ + t] = s;
  }
}

// softmax + weighted sum: grid = B*4, 256 thr, 512 f per block
__global__ __launch_bounds__(256) void wsum_k(const float* __restrict__ feat,
                                              const float* __restrict__ sp,
                                              float* __restrict__ out) {
  int b = blockIdx.x >> 2;
  int f0 = (blockIdx.x & 3) * 512;
  int t = threadIdx.x;
  __shared__ float lds_aw[R_];

  if (t < R_) {
    float s = sp[((size_t)b * 2 + 0) * R_ + t] + sp[((size_t)b * 2 + 1) * R_ + t];
    float m = s;
    #pragma unroll
    for (int off = 32; off >= 1; off >>= 1) m = fmaxf(m, __shfl_xor(m, off));
    float e = __expf(s - m);
    float su = e;
    #pragma unroll
    for (int off = 32; off >= 1; off >>= 1) su += __shfl_xor(su, off);
    lds_aw[t] = e / su;
  }
  __syncthreads();

  const float* fp = feat + (size_t)b * R_ * F_ + f0 + t * 2;
  float qx = 0.f, qy = 0.f;
  #pragma unroll 8
  for (int r = 0; r < R_; ++r) {
    float a = lds_aw[r];
    float2 v = *reinterpret_cast<const float2*>(fp + (size_t)r * F_);
    qx += a * v.x;
    qy += a * v.y;
  }
  *reinterpret_cast<float2*>(out + (size_t)b * F_ + f0 + t * 2) = (float2){qx, qy};
}

extern "C" void kernel_launch(void* const* d_in, const int* in_sizes, int n_in,
                              void* d_out, int out_size, void* d_ws, size_t ws_size,
                              hipStream_t stream) {
  const float* feat = (const float*)d_in[0];   // [B,R,F]
  const float* prev = (const float*)d_in[1];   // [B,H]
  const float* Ww   = (const float*)d_in[2];   // [F,DIM]
  const float* Wb   = (const float*)d_in[3];   // [DIM]
  const float* W2w  = (const float*)d_in[4];   // [H,DIM]
  const float* W2b  = (const float*)d_in[5];   // [DIM]
  const float* W3w  = (const float*)d_in[6];   // [DIM,1]
  // d_in[7] = W3_b: cancels in softmax
  float* out = (float*)d_out;

  ushort* wpack  = (ushort*)d_ws;                                          // 2 MB
  float*  pprime = (float*)((char*)d_ws + (size_t)F_ * DIM_ * 2);          // 512 KB
  float*  sp     = (float*)((char*)d_ws + (size_t)F_ * DIM_ * 2
                                        + (size_t)B_ * DIM_ * 4);          // 128 KB

  setup_k<<<4096 + 256, 256, 0, stream>>>(Ww, wpack, prev, W2w, W2b, Wb, pprime);
  score_k<<<B_ * 2, 256, 0, stream>>>(feat, wpack, pprime, W3w, sp);
  wsum_k<<<B_ * 4, 256, 0, stream>>>(feat, sp, out);
}